// Round 10
// baseline (125.631 us; speedup 1.0000x reference)
//
#include <hip/hip_runtime.h>

#define NN 10000
#define NE 320000
#define NPART 16

typedef short short8 __attribute__((ext_vector_type(8)));
typedef float f32x4 __attribute__((ext_vector_type(4)));

__device__ __forceinline__ unsigned short f2bf(float f) {
    unsigned u = __float_as_uint(f);
    return (unsigned short)((u + 0x7FFFu + ((u >> 16) & 1u)) >> 16);  // RNE
}
__device__ __forceinline__ float bflo(unsigned v) { return __uint_as_float(v << 16); }
__device__ __forceinline__ float bfhi(unsigned v) { return __uint_as_float(v & 0xffff0000u); }
__device__ __forceinline__ float bf1(unsigned short v) { return __uint_as_float(((unsigned)v) << 16); }

__device__ __forceinline__ int eread(const void* p, int is64, int i) {
    if (is64) return (int)((const long long*)p)[i];
    return ((const int*)p)[i];
}

// ---------- prep0: W1t cast | wrf fold | detect | zero partitioned deg ----------
__global__ __launch_bounds__(256) void k_prep0(const void* __restrict__ ei,
                                               const float* __restrict__ W1, const float* __restrict__ a1,
                                               unsigned short* __restrict__ W1t, float* __restrict__ wrf,
                                               int* __restrict__ flag, int* __restrict__ degp) {
    const int b = blockIdx.x, t = threadIdx.x;
    if (b < 256) {                        // W1t[h][j][k] = bf16(W1[k][h*128+j])
        const int g = b * 256 + t;
        const int h = g >> 14, j = (g >> 7) & 127, k = g & 127;
        W1t[g] = f2bf(W1[(size_t)k * 512 + h * 128 + j]);
    } else if (b < 258) {                 // wrf[h*128+k] = W1[k][h-blk] . a1[h][128:]
        const int g = (b - 256) * 256 + t;
        const int h = g >> 7, k = g & 127;
        const float* wrow = W1 + (size_t)k * 512 + h * 128;
        const float* av = a1 + h * 256 + 128;
        float s = 0.f;
        for (int d = 0; d < 128; d++) s += wrow[d] * av[d];
        wrf[h * 128 + k] = s;
    } else if (b == 258) {                // int64-vs-int32 detect
        if (t == 0) {
            const unsigned* idx = (const unsigned*)ei;
            int all0 = 1;
            for (int j = 1; j < 257; j += 2)
                if (idx[j] != 0u) { all0 = 0; break; }
            *flag = all0;
        }
    } else {                              // zero deg_cp + deg_rp (2*16*10000 ints)
        const int g = (b - 259) * 256 + t;
        if (g < 2 * NPART * NN) degp[g] = 0;
    }
}

// ---------- pre: blocks 0..2499 = xb cast + ehr1; 2500..3749 = partitioned hist+rank ----------
__global__ __launch_bounds__(256) void k_pre(const float* __restrict__ x, const float* __restrict__ wrf,
                                             unsigned short* __restrict__ xb, float* __restrict__ ehr1,
                                             const void* __restrict__ ei, const int* __restrict__ flag,
                                             int* __restrict__ deg_cp, int* __restrict__ deg_rp,
                                             unsigned* __restrict__ rank) {
    __shared__ float ls[512];
    const int b = blockIdx.x, t = threadIdx.x;
    if (b < 2500) {
        const int lane = t & 63, w = t >> 6;
        ls[t] = wrf[t];
        ls[t + 256] = wrf[t + 256];
        __syncthreads();
        const int i = b * 4 + w;
        const float x0 = x[(size_t)i * 128 + lane];
        const float x1 = x[(size_t)i * 128 + 64 + lane];
        xb[(size_t)i * 128 + lane]      = f2bf(x0);
        xb[(size_t)i * 128 + 64 + lane] = f2bf(x1);
        float v[4];
#pragma unroll
        for (int h = 0; h < 4; h++)
            v[h] = x0 * ls[h * 128 + lane] + x1 * ls[h * 128 + 64 + lane];
#pragma unroll
        for (int off = 1; off < 64; off <<= 1) {
#pragma unroll
            for (int j = 0; j < 4; j++) v[j] += __shfl_xor(v[j], off);
        }
        if (lane == 0)
            *(float4*)&ehr1[i * 4] = make_float4(__expf(v[0]), __expf(v[1]), __expf(v[2]), __expf(v[3]));
    } else {
        const int is64 = *flag;
        const int e = (b - 2500) * 256 + t;
        const int part = (e >> 8) & (NPART - 1);
        const int r = eread(ei, is64, e);
        const int c = eread(ei, is64, NE + e);
        const unsigned rkc = (unsigned)atomicAdd(deg_cp + part * NN + c, 1);
        const unsigned rkr = (unsigned)atomicAdd(deg_rp + part * NN + r, 1);
        rank[e] = rkc | (rkr << 16);
    }
}

// ---------- psum: per-node partition prefixes (u16) + totals ----------
__global__ __launch_bounds__(256) void k_psum(const int* __restrict__ deg_cp, const int* __restrict__ deg_rp,
                                              unsigned short* __restrict__ pfx_c, unsigned short* __restrict__ pfx_r,
                                              int* __restrict__ deg_c, int* __restrict__ deg_r) {
    const int g = blockIdx.x * 256 + threadIdx.x;
    if (g >= 2 * NN) return;
    const int arr = g / NN, node = g % NN;
    const int* degp = arr ? deg_rp : deg_cp;
    unsigned short* pfx = arr ? pfx_r : pfx_c;
    int* tot = arr ? deg_r : deg_c;
    int sum = 0;
    unsigned short loc[NPART];
#pragma unroll
    for (int p = 0; p < NPART; p++) {
        loc[p] = (unsigned short)sum;
        sum += degp[p * NN + node];
    }
    tot[node] = sum;
    uint4* dst = (uint4*)&pfx[(size_t)node * NPART];
    dst[0] = *(const uint4*)&loc[0];
    dst[1] = *(const uint4*)&loc[8];
}

// ---------- single-block (1024 thr) exclusive scan of deg_c and deg_r ----------
__device__ void scan_one_1k(const int* __restrict__ deg, int* __restrict__ start, int* ssum) {
    const int t = threadIdx.x;           // 0..1023
    int loc[10];
    const int base = t * 10;
    int sum = 0;
#pragma unroll
    for (int j = 0; j < 10; j++) {
        int i = base + j;
        int v = (i < NN) ? deg[i] : 0;
        loc[j] = sum;
        sum += v;
    }
    const int lane = t & 63, w = t >> 6; // w in 0..15
    int xi = sum;
#pragma unroll
    for (int off = 1; off < 64; off <<= 1) {
        int y = __shfl_up(xi, off);
        if (lane >= off) xi += y;
    }
    __syncthreads();
    if (lane == 63) ssum[w] = xi;
    __syncthreads();
    int woff = 0;
#pragma unroll
    for (int k = 0; k < 16; k++)
        if (k < w) woff += ssum[k];
    const int excl = woff + xi - sum;
#pragma unroll
    for (int j = 0; j < 10; j++) {
        int i = base + j;
        if (i < NN) start[i] = excl + loc[j];
    }
}

__global__ __launch_bounds__(1024) void k_scan2(const int* __restrict__ deg_c, const int* __restrict__ deg_r,
                                                int* __restrict__ start_c, int* __restrict__ start_r) {
    __shared__ int ssum[16];
    scan_one_1k(deg_c, start_c, ssum);
    __syncthreads();
    scan_one_1k(deg_r, start_r, ssum);
}

// ---------- build dual CSR from partition-local ranks (no atomics) ----------
__global__ __launch_bounds__(256) void k_build(const void* __restrict__ ei, const int* __restrict__ flag,
                                               const unsigned* __restrict__ rank,
                                               const unsigned short* __restrict__ pfx_c,
                                               const unsigned short* __restrict__ pfx_r,
                                               const int* __restrict__ start_c, const int* __restrict__ start_r,
                                               int* __restrict__ csrA, int* __restrict__ csrB) {
    const int is64 = *flag;
    const int e = blockIdx.x * blockDim.x + threadIdx.x;
    if (e >= NE) return;
    const int part = (e >> 8) & (NPART - 1);
    const int r = eread(ei, is64, e);
    const int c = eread(ei, is64, NE + e);
    const unsigned rk = rank[e];
    const int pc = (int)pfx_c[(size_t)c * NPART + part];
    const int pr = (int)pfx_r[(size_t)r * NPART + part];
    csrA[start_c[c] + pc + (int)(rk & 0xffffu)] = r;
    csrB[start_r[r] + pr + (int)(rk >> 16)] = c;
}

// ---------- rz1: 2 nodes per wave, 32 lanes each ----------
__global__ __launch_bounds__(256) void k_z1(const int* __restrict__ start_r, const int* __restrict__ deg_r,
                                            const int* __restrict__ csrB,
                                            const float* __restrict__ ehr1, float* __restrict__ rz1) {
    const int t = threadIdx.x, lane = t & 63, w = t >> 6;
    const int half = lane >> 5, l32 = lane & 31;
    const int i = blockIdx.x * 8 + w * 2 + half;
    const int s0 = start_r[i], d = deg_r[i];
    float zx = 0.f, zy = 0.f, zz = 0.f, zw = 0.f;
    for (int p = s0 + l32; p < s0 + d; p += 32) {
        const int c = csrB[p];
        const float4 v = *(const float4*)&ehr1[c * 4];
        zx += v.x; zy += v.y; zz += v.z; zw += v.w;
    }
#pragma unroll
    for (int off = 1; off < 32; off <<= 1) {
        zx += __shfl_xor(zx, off); zy += __shfl_xor(zy, off);
        zz += __shfl_xor(zz, off); zw += __shfl_xor(zw, off);
    }
    if (l32 == 0)
        *(float4*)&rz1[i * 4] = make_float4(1.f / zx, 1.f / zy, 1.f / zz, 1.f / zw);
}

// ---------- L1 aggregation on bf16 x, unroll-8 -> xaggb (bf16, [i][h][128]) ----------
__global__ __launch_bounds__(256) void k_agg1(const unsigned short* __restrict__ xb,
                                              const float* __restrict__ ehr1, const float* __restrict__ rz1,
                                              const int* __restrict__ start_c, const int* __restrict__ deg_c,
                                              const int* __restrict__ csrA,
                                              unsigned short* __restrict__ xaggb) {
    const int t = threadIdx.x, lane = t & 63, w = t >> 6;
    const int i = blockIdx.x * 4 + w;
    const float4 er4 = *(const float4*)&ehr1[i * 4];
    const int s0 = start_c[i], dg = deg_c[i];
    float acc[8];
#pragma unroll
    for (int j = 0; j < 8; j++) acc[j] = 0.f;
    int p = s0;
    const int e8 = s0 + (dg & ~7);
    for (; p < e8; p += 8) {
        int rr[8]; unsigned vv[8]; float4 zz[8];
#pragma unroll
        for (int q = 0; q < 8; q++) rr[q] = csrA[p + q];
#pragma unroll
        for (int q = 0; q < 8; q++) vv[q] = *(const unsigned*)&xb[(size_t)rr[q] * 128 + lane * 2];
#pragma unroll
        for (int q = 0; q < 8; q++) zz[q] = *(const float4*)&rz1[rr[q] * 4];
#pragma unroll
        for (int q = 0; q < 8; q++) {
            const float xa = bflo(vv[q]), xbv = bfhi(vv[q]);
            acc[0] += zz[q].x * xa; acc[1] += zz[q].x * xbv;
            acc[2] += zz[q].y * xa; acc[3] += zz[q].y * xbv;
            acc[4] += zz[q].z * xa; acc[5] += zz[q].z * xbv;
            acc[6] += zz[q].w * xa; acc[7] += zz[q].w * xbv;
        }
    }
    for (; p < s0 + dg; ++p) {
        const int r = csrA[p];
        const unsigned v = *(const unsigned*)&xb[(size_t)r * 128 + lane * 2];
        const float4 z = *(const float4*)&rz1[r * 4];
        const float xa = bflo(v), xbv = bfhi(v);
        acc[0] += z.x * xa; acc[1] += z.x * xbv;
        acc[2] += z.y * xa; acc[3] += z.y * xbv;
        acc[4] += z.z * xa; acc[5] += z.z * xbv;
        acc[6] += z.w * xa; acc[7] += z.w * xbv;
    }
    const float ef[4] = {er4.x, er4.y, er4.z, er4.w};
    unsigned short* op = xaggb + (size_t)i * 512 + lane * 2;
#pragma unroll
    for (int h = 0; h < 4; h++) {
        ushort2 st;
        st.x = f2bf(acc[h * 2] * ef[h]);
        st.y = f2bf(acc[h * 2 + 1] * ef[h]);
        *(ushort2*)(op + h * 128) = st;
    }
}

// ---------- MFMA GEMM: y[i,h,:] = xaggb[i,h,:]@W1h; h1m = mean_h ELU(y) ----------
__global__ __launch_bounds__(256) void k_gemmF(const unsigned short* __restrict__ xaggb,
                                               const unsigned short* __restrict__ W1t,
                                               float* __restrict__ h1m) {
    const int t = threadIdx.x, lane = t & 63, w = t >> 6;
    const int n0 = blockIdx.x * 32;
    const int r16 = lane & 15, grp = lane >> 4;
    const int jbase = w * 32;
    f32x4 hm[2][2];
#pragma unroll
    for (int m = 0; m < 2; m++)
#pragma unroll
        for (int n = 0; n < 2; n++) hm[m][n] = (f32x4)0.f;

#pragma unroll
    for (int h = 0; h < 4; h++) {
        f32x4 acc[2][2];
#pragma unroll
        for (int m = 0; m < 2; m++)
#pragma unroll
            for (int n = 0; n < 2; n++) acc[m][n] = (f32x4)0.f;
#pragma unroll
        for (int kk = 0; kk < 128; kk += 32) {
            const int k0 = kk + grp * 8;
            short8 a0 = *(const short8*)&xaggb[((size_t)(n0 + r16) * 4 + h) * 128 + k0];
            short8 a1 = *(const short8*)&xaggb[((size_t)(n0 + 16 + r16) * 4 + h) * 128 + k0];
            short8 b0 = *(const short8*)&W1t[(size_t)h * 16384 + (jbase + r16) * 128 + k0];
            short8 b1 = *(const short8*)&W1t[(size_t)h * 16384 + (jbase + 16 + r16) * 128 + k0];
            acc[0][0] = __builtin_amdgcn_mfma_f32_16x16x32_bf16(a0, b0, acc[0][0], 0, 0, 0);
            acc[1][0] = __builtin_amdgcn_mfma_f32_16x16x32_bf16(a1, b0, acc[1][0], 0, 0, 0);
            acc[0][1] = __builtin_amdgcn_mfma_f32_16x16x32_bf16(a0, b1, acc[0][1], 0, 0, 0);
            acc[1][1] = __builtin_amdgcn_mfma_f32_16x16x32_bf16(a1, b1, acc[1][1], 0, 0, 0);
        }
#pragma unroll
        for (int m = 0; m < 2; m++)
#pragma unroll
            for (int n = 0; n < 2; n++)
#pragma unroll
                for (int r = 0; r < 4; r++) {
                    const float v = acc[m][n][r];
                    hm[m][n][r] += (v > 0.f) ? v : (__expf(v) - 1.f);  // ELU
                }
    }
#pragma unroll
    for (int m = 0; m < 2; m++)
#pragma unroll
        for (int n = 0; n < 2; n++)
#pragma unroll
            for (int r = 0; r < 4; r++) {
                const int node = n0 + m * 16 + grp * 4 + r;
                const int col = jbase + n * 16 + r16;
                h1m[(size_t)node * 128 + col] = 0.25f * hm[m][n][r];
            }
}

// ---------- Layer-2 GEMM (k-split across lane halves) + exp(hr2) ----------
__global__ __launch_bounds__(256) void k_gemm2(const float* __restrict__ h1m, const float* __restrict__ W2,
                                               const float* __restrict__ a2,
                                               float* __restrict__ h2, float* __restrict__ ehr2) {
    __shared__ float sh[4][128];
    const int t = threadIdx.x, lane = t & 63, w = t >> 6;
    const int i = blockIdx.x * 4 + w;
    sh[w][lane]      = h1m[(size_t)i * 128 + lane];
    sh[w][lane + 64] = h1m[(size_t)i * 128 + 64 + lane];
    __syncthreads();
    const int seg = lane >> 5, c = lane & 31;
    float part = 0.f;
    if (c < 22) {
        const int kb = seg * 64;
        for (int k = kb; k < kb + 64; k++)
            part += sh[w][k] * W2[k * 22 + c];
    }
    part += __shfl_xor(part, 32);
    const float acc = part;
    if (lane < 22) h2[(size_t)i * 22 + lane] = acc;
    float pr = (lane < 22) ? acc * a2[22 + lane] : 0.f;
#pragma unroll
    for (int off = 1; off < 64; off <<= 1)
        pr += __shfl_xor(pr, off);
    if (lane == 0) ehr2[i] = __expf(pr);
}

// ---------- z2 + fold: h2s[i][c] = bf16(h2[i][c] / z2[i]) ----------
__global__ __launch_bounds__(256) void k_z2s(const int* __restrict__ start_r, const int* __restrict__ deg_r,
                                             const int* __restrict__ csrB,
                                             const float* __restrict__ ehr2, const float* __restrict__ h2,
                                             unsigned short* __restrict__ h2s) {
    const int t = threadIdx.x, lane = t & 63, w = t >> 6;
    const int half = lane >> 5, l32 = lane & 31;
    const int i = blockIdx.x * 8 + w * 2 + half;
    const int s0 = start_r[i], d = deg_r[i];
    float z = 0.f;
    for (int p = s0 + l32; p < s0 + d; p += 32)
        z += ehr2[csrB[p]];
#pragma unroll
    for (int off = 1; off < 32; off <<= 1)
        z += __shfl_xor(z, off);          // all 32 lanes now hold the sum
    const float rz = 1.f / z;
    if (l32 < 22)
        h2s[(size_t)i * 22 + l32] = f2bf(h2[(size_t)i * 22 + l32] * rz);
}

// ---------- L2 aggregation: 2 nodes/wave, bf16 h2s gather, unroll-4 ----------
__global__ __launch_bounds__(256) void k_agg2(const unsigned short* __restrict__ h2s,
                                              const float* __restrict__ ehr2,
                                              const int* __restrict__ start_c, const int* __restrict__ deg_c,
                                              const int* __restrict__ csrA,
                                              float* __restrict__ out) {
    const int t = threadIdx.x, lane = t & 63, w = t >> 6;
    const int half = lane >> 5, c32 = lane & 31;
    const int i = blockIdx.x * 8 + w * 2 + half;
    const int s0 = start_c[i], dg = deg_c[i];
    const float e2 = ehr2[i];
    const int c = (c32 < 22) ? c32 : 0;
    float acc = 0.f;
    int p = s0;
    const int e4 = s0 + (dg & ~3);
    for (; p < e4; p += 4) {
        const int r0 = csrA[p], r1 = csrA[p + 1], r2 = csrA[p + 2], r3 = csrA[p + 3];
        const float v0 = bf1(h2s[(size_t)r0 * 22 + c]);
        const float v1 = bf1(h2s[(size_t)r1 * 22 + c]);
        const float v2 = bf1(h2s[(size_t)r2 * 22 + c]);
        const float v3 = bf1(h2s[(size_t)r3 * 22 + c]);
        acc += v0 + v1 + v2 + v3;
    }
    for (; p < s0 + dg; ++p) {
        const int r = csrA[p];
        acc += bf1(h2s[(size_t)r * 22 + c]);
    }
    if (c32 < 22) out[(size_t)i * 22 + c32] = acc * e2;
}

extern "C" void kernel_launch(void* const* d_in, const int* in_sizes, int n_in,
                              void* d_out, int out_size, void* d_ws, size_t ws_size,
                              hipStream_t stream) {
    const float* x  = (const float*)d_in[0];
    const void*  ei = d_in[1];
    const float* W1 = (const float*)d_in[2];
    const float* a1 = (const float*)d_in[3];
    const float* W2 = (const float*)d_in[4];
    const float* a2 = (const float*)d_in[5];
    float* out = (float*)d_out;

    float* ws = (float*)d_ws;
    unsigned short* xaggb = (unsigned short*)ws;        // 10016*512 ushorts
    float* h1m  = ws + 2600000;                         // 10016*128 (padded)
    float* h2   = ws + 3890000;                         //   220,000
    float* ehr1 = ws + 4110000;                         //    40,000
    float* rz1  = ws + 4150000;                         //    40,000
    float* ehr2 = ws + 4190000;                         //    10,000
    unsigned short* h2s = (unsigned short*)(ws + 4200000);  // 220,000 ushorts
    int* deg_c   = (int*)(ws + 4310000);                //    10,000 (totals)
    int* deg_r   = (int*)(ws + 4320000);                //    10,000
    int* start_c = (int*)(ws + 4330000);
    int* start_r = (int*)(ws + 4340000);
    int* csrA    = (int*)(ws + 4350000);                //   320,000
    int* csrB    = (int*)(ws + 4670000);                //   320,000
    int* flag    = (int*)(ws + 4990000);
    float* wrf   = ws + 4990064;                        //       512
    unsigned short* W1t = (unsigned short*)(ws + 4991000);  //  65,536 ushorts
    unsigned short* xb  = (unsigned short*)(ws + 5024000);  // 1,280,000 ushorts
    unsigned* rank = (unsigned*)(ws + 5664000);             //   320,000 uints
    int* deg_cp = (int*)(ws + 5984000);                 // 16*10,000
    int* deg_rp = (int*)(ws + 6144000);                 // 16*10,000
    unsigned short* pfx_c = (unsigned short*)(ws + 6304000);  // 160,000 ushorts
    unsigned short* pfx_r = (unsigned short*)(ws + 6384000);  // 160,000 ushorts

    k_prep0<<<1509, 256, 0, stream>>>(ei, W1, a1, W1t, wrf, flag, deg_cp);
    k_pre<<<3750, 256, 0, stream>>>(x, wrf, xb, ehr1, ei, flag, deg_cp, deg_rp, rank);
    k_psum<<<79, 256, 0, stream>>>(deg_cp, deg_rp, pfx_c, pfx_r, deg_c, deg_r);
    k_scan2<<<1, 1024, 0, stream>>>(deg_c, deg_r, start_c, start_r);
    k_build<<<1250, 256, 0, stream>>>(ei, flag, rank, pfx_c, pfx_r, start_c, start_r, csrA, csrB);
    k_z1<<<1250, 256, 0, stream>>>(start_r, deg_r, csrB, ehr1, rz1);
    k_agg1<<<2500, 256, 0, stream>>>(xb, ehr1, rz1, start_c, deg_c, csrA, xaggb);
    k_gemmF<<<313, 256, 0, stream>>>(xaggb, W1t, h1m);
    k_gemm2<<<2500, 256, 0, stream>>>(h1m, W2, a2, h2, ehr2);
    k_z2s<<<1250, 256, 0, stream>>>(start_r, deg_r, csrB, ehr2, h2, h2s);
    k_agg2<<<1250, 256, 0, stream>>>(h2s, ehr2, start_c, deg_c, csrA, out);
}